// Round 3
// baseline (336.022 us; speedup 1.0000x reference)
//
#include <hip/hip_runtime.h>
#include <math.h>

#define B 32
#define S 512
#define Q 512
#define I 256
#define O 64
#define SIG_EPS 0.1f
#define LOG_SIG_EPS (-2.3025850929940457f)

// f32 workspace offsets
#define WS_L 0                  // 65536
#define WS_T1 65536             // 16384
#define WS_LKT 81920            // 16384  (f32 [64][256], LK transposed)
#define WS_M0 98304             // B*65536
#define WS_M1 2195456           // B*65536
#define WS_RHST 4292608         // B*16384 (f32 [64][256] per b, transposed)
#define WS_D 4816896            // 2*B*4096
#define WS_SP 5079040           // B*512
#define WS_NLL 5095424          // 64
#define WS_U16 5095488          // u16 arrays start here (cast)
// u16 offsets (units of u16) from u16 base
#define U_PTH 0                 // B*256*512 = 4194304
#define U_PTL 4194304
#define U_YTH 8388608           // B*64*512 = 1048576
#define U_YTL 9437184
#define U_IVH 10485760          // B*256*256 = 2097152
#define U_IVL 12582912
#define U_PKH 14680064          // B*64*256 = 524288
#define U_PKL 15204352

#define OUT_MU_ELEMS (B * Q * O)
#define OUT_SIG_ELEMS (B * Q * O * O)
#define OUT_NLL_IDX (OUT_MU_ELEMS + OUT_SIG_ELEMS)

typedef short short8 __attribute__((ext_vector_type(8)));
typedef float f32x4 __attribute__((ext_vector_type(4)));
#define MFMA16(a, b, c) __builtin_amdgcn_mfma_f32_16x16x32_bf16(a, b, c, 0, 0, 0)

__device__ __forceinline__ f32x4 mfma3(short8 ah, short8 al, short8 bh, short8 bl, f32x4 c) {
  c = MFMA16(ah, bh, c);
  c = MFMA16(ah, bl, c);
  c = MFMA16(al, bh, c);
  return c;
}

__device__ __forceinline__ unsigned short f2bf(float x) {
  unsigned int u = __float_as_uint(x);
  return (unsigned short)((u + 0x7fffu + ((u >> 16) & 1u)) >> 16);
}
__device__ __forceinline__ float bf2f(unsigned short h) { return __uint_as_float(((unsigned int)h) << 16); }
__device__ __forceinline__ void split2(float x, unsigned short& h, unsigned short& l) {
  h = f2bf(x);
  l = f2bf(x - bf2f(h));
}
__device__ __forceinline__ void split4(float4 v, uint2& H, uint2& L) {
  unsigned short h0, h1, h2, h3, l0, l1, l2, l3;
  split2(v.x, h0, l0); split2(v.y, h1, l1); split2(v.z, h2, l2); split2(v.w, h3, l3);
  H.x = (unsigned)h0 | ((unsigned)h1 << 16); H.y = (unsigned)h2 | ((unsigned)h3 << 16);
  L.x = (unsigned)l0 | ((unsigned)l1 << 16); L.y = (unsigned)l2 | ((unsigned)l3 << 16);
}
// convert 8 consecutive f32 at p -> hi/lo short8 frags
__device__ __forceinline__ void cvt8(const float* p, short8& h8, short8& l8) {
  float4 a = *(const float4*)p;
  float4 b = *(const float4*)(p + 4);
  uint2 H0, L0, H1, L1;
  split4(a, H0, L0); split4(b, H1, L1);
  union { uint2 q[2]; short8 s; } uh, ul;
  uh.q[0] = H0; uh.q[1] = H1; ul.q[0] = L0; ul.q[1] = L1;
  h8 = uh.s; l8 = ul.s;
}
__device__ __forceinline__ short8 ld8(const unsigned short* p) { return *(const short8*)(const void*)p; }

__device__ __forceinline__ void fma4x4(const float4 av, const float4 bv, float acc[4][4]) {
  const float ar[4] = {av.x, av.y, av.z, av.w};
  const float br[4] = {bv.x, bv.y, bv.z, bv.w};
#pragma unroll
  for (int i = 0; i < 4; ++i)
#pragma unroll
    for (int j = 0; j < 4; ++j) acc[i][j] += ar[i] * br[j];
}

__device__ __forceinline__ void load_direct64(float* dst, int ds, const float* src, int ss, int t) {
#pragma unroll
  for (int m = 0; m < 4; ++m) {
    int r = (t >> 4) + 16 * m, c4 = (t & 15) * 4;
    *(float4*)&dst[r * ds + c4] = *(const float4*)&src[(size_t)r * ss + c4];
  }
}
__device__ __forceinline__ void load_trans64(float* dst, int ds, const float* src, int ss, int t) {
#pragma unroll
  for (int m = 0; m < 4; ++m) {
    int r = (t >> 4) + 16 * m, c4 = (t & 15) * 4;
    float4 v = *(const float4*)&src[(size_t)r * ss + c4];
    dst[(c4 + 0) * ds + r] = v.x;
    dst[(c4 + 1) * ds + r] = v.y;
    dst[(c4 + 2) * ds + r] = v.z;
    dst[(c4 + 3) * ds + r] = v.w;
  }
}
template <int SA, int SB>
__device__ __forceinline__ void gemm64(const float* At, const float* Bs, int tr, int tc, float acc[4][4]) {
#pragma unroll 8
  for (int kk = 0; kk < 64; ++kk) {
    float4 a = *(const float4*)&At[kk * SA + tr * 4];
    float4 b = *(const float4*)&Bs[kk * SB + tc * 4];
    fma4x4(a, b, acc);
  }
}

#define SC4(V) V.x *= pivinv; V.y *= pivinv; V.z *= pivinv; V.w *= pivinv
#define UP4(V, R) V.x -= g * R.x; V.y -= g * R.y; V.z -= g * R.z; V.w -= g * R.w

template <int TS>
__device__ void gj64(const float* T, float* rowbuf, float* Dout, int t) {
  int r = t >> 2, q = t & 3;
  int lane = t & 63;
  float4 A0 = *(const float4*)&T[r * TS + q * 16 + 0];
  float4 A1 = *(const float4*)&T[r * TS + q * 16 + 4];
  float4 A2 = *(const float4*)&T[r * TS + q * 16 + 8];
  float4 A3 = *(const float4*)&T[r * TS + q * 16 + 12];
#define IC(c) (((q * 16 + (c)) == r) ? 1.f : 0.f)
  float4 I0 = make_float4(IC(0), IC(1), IC(2), IC(3));
  float4 I1 = make_float4(IC(4), IC(5), IC(6), IC(7));
  float4 I2 = make_float4(IC(8), IC(9), IC(10), IC(11));
  float4 I3 = make_float4(IC(12), IC(13), IC(14), IC(15));
#undef IC
  for (int p = 0; p < 64; ++p) {
    float* RA = rowbuf + (p & 1) * 128;
    float* RI = RA + 64;
    if (r == p) {
      ((float4*)&RA[q * 16])[0] = A0; ((float4*)&RA[q * 16])[1] = A1;
      ((float4*)&RA[q * 16])[2] = A2; ((float4*)&RA[q * 16])[3] = A3;
      ((float4*)&RI[q * 16])[0] = I0; ((float4*)&RI[q * 16])[1] = I1;
      ((float4*)&RI[q * 16])[2] = I2; ((float4*)&RI[q * 16])[3] = I3;
    }
    __syncthreads();
    float pivinv = 1.0f / RA[p];
    int s = p & 15;
    float4 blk = (s < 8) ? ((s < 4) ? A0 : A1) : ((s < 12) ? A2 : A3);
    int sc = s & 3;
    float ap = (sc == 0) ? blk.x : (sc == 1) ? blk.y : (sc == 2) ? blk.z : blk.w;
    float f = __shfl(ap, (lane & ~3) | (p >> 4), 64);
    float4 ra0 = ((const float4*)&RA[q * 16])[0], ra1 = ((const float4*)&RA[q * 16])[1];
    float4 ra2 = ((const float4*)&RA[q * 16])[2], ra3 = ((const float4*)&RA[q * 16])[3];
    float4 ri0 = ((const float4*)&RI[q * 16])[0], ri1 = ((const float4*)&RI[q * 16])[1];
    float4 ri2 = ((const float4*)&RI[q * 16])[2], ri3 = ((const float4*)&RI[q * 16])[3];
    if (r == p) {
      SC4(A0); SC4(A1); SC4(A2); SC4(A3);
      SC4(I0); SC4(I1); SC4(I2); SC4(I3);
    } else {
      float g = f * pivinv;
      UP4(A0, ra0); UP4(A1, ra1); UP4(A2, ra2); UP4(A3, ra3);
      UP4(I0, ri0); UP4(I1, ri1); UP4(I2, ri2); UP4(I3, ri3);
    }
  }
  ((float4*)&Dout[r * 64 + q * 16])[0] = I0;
  ((float4*)&Dout[r * 64 + q * 16])[1] = I1;
  ((float4*)&Dout[r * 64 + q * 16])[2] = I2;
  ((float4*)&Dout[r * 64 + q * 16])[3] = I3;
}

// ---------------- cvt: transpose+split phi_s -> PT (b,256,512), y_s -> YT (b,64,512); nll init ----------------
__global__ __launch_bounds__(256) void k_cvt(const float* __restrict__ phi_s, const float* __restrict__ y_s,
                                             unsigned short* __restrict__ PTh, unsigned short* __restrict__ PTl,
                                             unsigned short* __restrict__ YTh, unsigned short* __restrict__ YTl,
                                             float* __restrict__ nllacc) {
  __shared__ unsigned short Hs[64][68];
  __shared__ unsigned short Lo[64][68];
  int blk = blockIdx.x, t = threadIdx.x;
  if (blk == 0 && t == 0) nllacc[0] = 0.f;
  const float* src;
  unsigned short *dh, *dl;
  int sstride;
  if (blk < 1024) {
    int b = blk >> 5, r = blk & 31, ic = r >> 3, sc = r & 7;
    src = phi_s + ((size_t)b * 512 + sc * 64) * 256 + ic * 64;
    sstride = 256;
    size_t d0 = ((size_t)b * 256 + ic * 64) * 512 + sc * 64;
    dh = PTh + d0; dl = PTl + d0;
  } else {
    int qq = blk - 1024, b = qq >> 3, sc = qq & 7;
    src = y_s + ((size_t)b * 512 + sc * 64) * 64;
    sstride = 64;
    size_t d0 = ((size_t)b * 64) * 512 + sc * 64;
    dh = YTh + d0; dl = YTl + d0;
  }
  int c = t & 63, rb = (t >> 6) * 16;
#pragma unroll
  for (int m = 0; m < 16; ++m) {
    int s = rb + m;
    float x = src[(size_t)s * sstride + c];
    unsigned short h, l;
    split2(x, h, l);
    Hs[c][s] = h;
    Lo[c][s] = l;
  }
  __syncthreads();
  int il0 = t >> 4, c4 = (t & 15) * 4;
#pragma unroll
  for (int m = 0; m < 4; ++m) {
    int il = il0 + 16 * m;
    uint2 H, L;
    H.x = (unsigned)Hs[il][c4] | ((unsigned)Hs[il][c4 + 1] << 16);
    H.y = (unsigned)Hs[il][c4 + 2] | ((unsigned)Hs[il][c4 + 3] << 16);
    L.x = (unsigned)Lo[il][c4] | ((unsigned)Lo[il][c4 + 1] << 16);
    L.y = (unsigned)Lo[il][c4 + 2] | ((unsigned)Lo[il][c4 + 3] << 16);
    *(uint2*)&dh[(size_t)il * 512 + c4] = H;
    *(uint2*)&dl[(size_t)il * 512 + c4] = L;
  }
}

// ---------------- pre1: L = La La^T (16 tiles) + T1 = La^T K (4 tiles) ----------------
__global__ __launch_bounds__(256) void k_pre1(const float* __restrict__ La, const float* __restrict__ Km,
                                              float* __restrict__ Lm, float* __restrict__ T1) {
  __shared__ float sA[16 * 68];
  __shared__ float sB[16 * 68];
  int blk = blockIdx.x, t = threadIdx.x;
  int tr = t >> 4, tc = t & 15;
  float acc[4][4] = {};
  if (blk < 16) {
    int i0 = (blk >> 2) * 64, j0 = (blk & 3) * 64;
    for (int ks = 0; ks < 256; ks += 16) {
      __syncthreads();
#pragma unroll
      for (int m = 0; m < 4; ++m) {
        int r = (t >> 4) + 16 * m, kk = t & 15;
        sA[kk * 68 + r] = La[(size_t)(i0 + r) * 256 + ks + kk];
        sB[kk * 68 + r] = La[(size_t)(j0 + r) * 256 + ks + kk];
      }
      __syncthreads();
#pragma unroll
      for (int kk = 0; kk < 16; ++kk) {
        float4 a = *(const float4*)&sA[kk * 68 + tr * 4];
        float4 bv = *(const float4*)&sB[kk * 68 + tc * 4];
        fma4x4(a, bv, acc);
      }
    }
#pragma unroll
    for (int mi = 0; mi < 4; ++mi) {
      float4 v = {acc[mi][0], acc[mi][1], acc[mi][2], acc[mi][3]};
      *(float4*)&Lm[(size_t)(i0 + tr * 4 + mi) * 256 + j0 + tc * 4] = v;
    }
  } else {
    int i0 = (blk - 16) * 64;
    for (int ks = 0; ks < 256; ks += 16) {
      __syncthreads();
#pragma unroll
      for (int m = 0; m < 4; ++m) {
        int kk = (t >> 6) + 4 * m, c = t & 63;
        sA[kk * 68 + c] = La[(size_t)(ks + kk) * 256 + i0 + c];
        sB[kk * 68 + c] = Km[(size_t)(ks + kk) * 64 + c];
      }
      __syncthreads();
#pragma unroll
      for (int kk = 0; kk < 16; ++kk) {
        float4 a = *(const float4*)&sA[kk * 68 + tr * 4];
        float4 bv = *(const float4*)&sB[kk * 68 + tc * 4];
        fma4x4(a, bv, acc);
      }
    }
#pragma unroll
    for (int mi = 0; mi < 4; ++mi) {
      float4 v = {acc[mi][0], acc[mi][1], acc[mi][2], acc[mi][3]};
      *(float4*)&T1[(size_t)(i0 + tr * 4 + mi) * 64 + tc * 4] = v;
    }
  }
}

// ---------------- gram (MFMA): M tiles (sym+mirror), RHST, LK->LKT, D0 fold ----------------
__global__ __launch_bounds__(256) void k_gram(
    const unsigned short* __restrict__ PTh, const unsigned short* __restrict__ PTl,
    const unsigned short* __restrict__ YTh, const unsigned short* __restrict__ YTl,
    const float* __restrict__ Lm, const float* __restrict__ La, const float* __restrict__ T1,
    float* __restrict__ M0, float* __restrict__ RHST, float* __restrict__ LKT, float* __restrict__ Dbuf) {
  __shared__ float trbuf[64 * 68];
  __shared__ float rowbuf[256];
  __shared__ float Ws[16 * 64];
  int b = blockIdx.x, y = blockIdx.y, t = threadIdx.x;

  if (y == 14) {  // LK = La @ T1, write LKT[o][i]
    if (b >= 4) return;
    int i0 = b * 64;
    int tr = t >> 4, tc = t & 15;
    float acc[4][4] = {};
    for (int ks = 0; ks < 256; ks += 16) {
      __syncthreads();
#pragma unroll
      for (int m = 0; m < 4; ++m) {
        trbuf[(t & 15) * 68 + (t >> 4) + 16 * m] = La[(size_t)(i0 + (t >> 4) + 16 * m) * 256 + ks + (t & 15)];
        Ws[((t >> 6) + 4 * m) * 64 + (t & 63)] = T1[(size_t)(ks + (t >> 6) + 4 * m) * 64 + (t & 63)];
      }
      __syncthreads();
#pragma unroll
      for (int kk = 0; kk < 16; ++kk) {
        float4 a = *(const float4*)&trbuf[kk * 68 + tr * 4];
        float4 bv = *(const float4*)&Ws[kk * 64 + tc * 4];
        fma4x4(a, bv, acc);
      }
    }
    __syncthreads();
#pragma unroll
    for (int mi = 0; mi < 4; ++mi)
#pragma unroll
      for (int cj = 0; cj < 4; ++cj) trbuf[(tr * 4 + mi) * 68 + tc * 4 + cj] = acc[mi][cj];
    __syncthreads();
    int rr0 = t >> 4, cc4 = (t & 15) * 4;
#pragma unroll
    for (int m = 0; m < 4; ++m) {
      int rr = rr0 + 16 * m;
      float4 v = {trbuf[(cc4 + 0) * 68 + rr], trbuf[(cc4 + 1) * 68 + rr], trbuf[(cc4 + 2) * 68 + rr],
                  trbuf[(cc4 + 3) * 68 + rr]};
      *(float4*)&LKT[(size_t)rr * 256 + i0 + cc4] = v;
    }
    return;
  }

  const int TIa[14] = {0, 0, 0, 0, 1, 1, 1, 2, 2, 3, 0, 1, 2, 3};
  const int TJa[14] = {0, 1, 2, 3, 1, 2, 3, 2, 3, 3, 0, 0, 0, 0};
  bool isR = (y >= 10);
  int it = TIa[y], jt = TJa[y];
  int i0 = it * 64, j0 = isR ? 0 : jt * 64;
  int lane = t & 63, w = t >> 6, wr = w >> 1, wc = w & 1;
  const unsigned short* Ah = PTh + (size_t)b * 256 * 512;
  const unsigned short* Al = PTl + (size_t)b * 256 * 512;
  const unsigned short* Bh = isR ? (YTh + (size_t)b * 64 * 512) : Ah;
  const unsigned short* Bl = isR ? (YTl + (size_t)b * 64 * 512) : Al;
  int ra0 = i0 + wr * 32 + (lane & 15);
  int rb0 = j0 + wc * 32 + (lane & 15);
  int klane = (lane >> 4) * 8;
  f32x4 acc[2][2] = {};
  for (int ks = 0; ks < 512; ks += 32) {
    int kk = ks + klane;
    short8 a0h = ld8(Ah + (size_t)ra0 * 512 + kk);
    short8 a1h = ld8(Ah + (size_t)(ra0 + 16) * 512 + kk);
    short8 a0l = ld8(Al + (size_t)ra0 * 512 + kk);
    short8 a1l = ld8(Al + (size_t)(ra0 + 16) * 512 + kk);
    short8 b0h = ld8(Bh + (size_t)rb0 * 512 + kk);
    short8 b1h = ld8(Bh + (size_t)(rb0 + 16) * 512 + kk);
    short8 b0l = ld8(Bl + (size_t)rb0 * 512 + kk);
    short8 b1l = ld8(Bl + (size_t)(rb0 + 16) * 512 + kk);
    acc[0][0] = mfma3(a0h, a0l, b0h, b0l, acc[0][0]);
    acc[0][1] = mfma3(a0h, a0l, b1h, b1l, acc[0][1]);
    acc[1][0] = mfma3(a1h, a1l, b0h, b0l, acc[1][0]);
    acc[1][1] = mfma3(a1h, a1l, b1h, b1l, acc[1][1]);
  }
#pragma unroll
  for (int ti = 0; ti < 2; ++ti)
#pragma unroll
    for (int tj = 0; tj < 2; ++tj)
#pragma unroll
      for (int r = 0; r < 4; ++r)
        trbuf[(wr * 32 + ti * 16 + (lane >> 4) * 4 + r) * 68 + wc * 32 + tj * 16 + (lane & 15)] = acc[ti][tj][r];
  __syncthreads();
  int rr0 = t >> 4, cc4 = (t & 15) * 4;
  if (!isR) {
    float* Mb = M0 + (size_t)b * 65536;
    bool d00 = (it == 0 && jt == 0);
#pragma unroll
    for (int m = 0; m < 4; ++m) {
      int rr = rr0 + 16 * m;
      float4 v = *(float4*)&trbuf[rr * 68 + cc4];
      float4 lv = *(const float4*)&Lm[(size_t)(i0 + rr) * 256 + j0 + cc4];
      v.x += lv.x; v.y += lv.y; v.z += lv.z; v.w += lv.w;
      *(float4*)&Mb[(size_t)(i0 + rr) * 256 + j0 + cc4] = v;
      if (d00) *(float4*)&trbuf[rr * 68 + cc4] = v;
    }
    if (it != jt) {
#pragma unroll
      for (int m = 0; m < 4; ++m) {
        int rr = rr0 + 16 * m;
        float4 v = {trbuf[(cc4 + 0) * 68 + rr], trbuf[(cc4 + 1) * 68 + rr], trbuf[(cc4 + 2) * 68 + rr],
                    trbuf[(cc4 + 3) * 68 + rr]};
        float4 lv = *(const float4*)&Lm[(size_t)(j0 + rr) * 256 + i0 + cc4];
        v.x += lv.x; v.y += lv.y; v.z += lv.z; v.w += lv.w;
        *(float4*)&Mb[(size_t)(j0 + rr) * 256 + i0 + cc4] = v;
      }
    }
    if (d00) {
      __syncthreads();
      gj64<68>(trbuf, rowbuf, Dbuf + (size_t)b * 4096, t);
    }
  } else {
#pragma unroll
    for (int m = 0; m < 4; ++m) {
      int rr = rr0 + 16 * m;  // o index
      float4 v = {trbuf[(cc4 + 0) * 68 + rr], trbuf[(cc4 + 1) * 68 + rr], trbuf[(cc4 + 2) * 68 + rr],
                  trbuf[(cc4 + 3) * 68 + rr]};
      *(float4*)&RHST[((size_t)b * 64 + rr) * 256 + i0 + cc4] = v;
    }
  }
}

// ---------------- blocked-GJ step, ping-pong src->dst; kb==3 writes split-bf16 Minv ----------------
__global__ __launch_bounds__(256) void k_step(const float* __restrict__ Msrc_, float* __restrict__ Mdst_,
                                              float* __restrict__ Dbuf, unsigned short* __restrict__ IVh,
                                              unsigned short* __restrict__ IVl, int kb) {
  __shared__ float shA[64 * 68];
  __shared__ float shB[64 * 64];
  __shared__ float shC[64 * 64];
  __shared__ float shD[64 * 68];
  __shared__ float rowbuf[256];
  int b = blockIdx.x, u = blockIdx.y;
  int i = u >> 2, j = u & 3;
  int t = threadIdx.x;
  int tr = t >> 4, tc = t & 15;
  const float* Ms = Msrc_ + (size_t)b * 65536;
  float* Md = Mdst_ + (size_t)b * 65536;
  const float* Din = Dbuf + (size_t)(kb & 1) * (B * 4096) + (size_t)b * 4096;
  float* Dout = Dbuf + (size_t)((kb + 1) & 1) * (B * 4096) + (size_t)b * 4096;
  bool last = (kb == 3);
  unsigned short* Yh = IVh + (size_t)b * 65536;
  unsigned short* Yl = IVl + (size_t)b * 65536;
  auto STORE = [&](int row, int col, float4 v) {
    if (last) {
      uint2 H, L;
      split4(v, H, L);
      *(uint2*)&Yh[(size_t)row * 256 + col] = H;
      *(uint2*)&Yl[(size_t)row * 256 + col] = L;
    } else {
      *(float4*)&Md[(size_t)row * 256 + col] = v;
    }
  };
  bool ik = (i == kb), jk = (j == kb);
  if (ik && jk) {
#pragma unroll
    for (int m = 0; m < 4; ++m) {
      int r = (t >> 4) + 16 * m, c4 = (t & 15) * 4;
      STORE(kb * 64 + r, kb * 64 + c4, *(const float4*)&Din[r * 64 + c4]);
    }
    return;
  }
  float acc[4][4] = {};
  if (ik) {  // M'[kb][j] = D * M[kb][j]
    load_trans64(shA, 68, Din, 64, t);
    load_direct64(shB, 64, &Ms[(size_t)(kb * 64) * 256 + j * 64], 256, t);
    __syncthreads();
    gemm64<68, 64>(shA, shB, tr, tc, acc);
#pragma unroll
    for (int mi = 0; mi < 4; ++mi) {
      float4 v = {acc[mi][0], acc[mi][1], acc[mi][2], acc[mi][3]};
      STORE(kb * 64 + tr * 4 + mi, j * 64 + tc * 4, v);
    }
    return;
  }
  if (jk) {  // M'[i][kb] = -M[i][kb] * D
    load_trans64(shA, 68, &Ms[(size_t)(i * 64) * 256 + kb * 64], 256, t);
    load_direct64(shB, 64, Din, 64, t);
    __syncthreads();
    gemm64<68, 64>(shA, shB, tr, tc, acc);
#pragma unroll
    for (int mi = 0; mi < 4; ++mi) {
      float4 v = {-acc[mi][0], -acc[mi][1], -acc[mi][2], -acc[mi][3]};
      STORE(i * 64 + tr * 4 + mi, kb * 64 + tc * 4, v);
    }
    return;
  }
  // update: T = D*M[kb][j]; M'[i][j] = M[i][j] - M[i][kb]*T
  load_trans64(shA, 68, Din, 64, t);
  load_direct64(shB, 64, &Ms[(size_t)(kb * 64) * 256 + j * 64], 256, t);
  load_trans64(shD, 68, &Ms[(size_t)(i * 64) * 256 + kb * 64], 256, t);
  __syncthreads();
  gemm64<68, 64>(shA, shB, tr, tc, acc);
#pragma unroll
  for (int mi = 0; mi < 4; ++mi) {
    float4 v = {acc[mi][0], acc[mi][1], acc[mi][2], acc[mi][3]};
    *(float4*)&shC[(tr * 4 + mi) * 64 + tc * 4] = v;
  }
  __syncthreads();
  float acc2[4][4] = {};
  gemm64<68, 64>(shD, shC, tr, tc, acc2);
  bool la = (kb < 3) && (i == kb + 1) && (j == kb + 1);
#pragma unroll
  for (int mi = 0; mi < 4; ++mi) {
    size_t off = (size_t)(i * 64 + tr * 4 + mi) * 256 + j * 64 + tc * 4;
    float4 old = *(const float4*)&Ms[off];
    float4 v = {old.x - acc2[mi][0], old.y - acc2[mi][1], old.z - acc2[mi][2], old.w - acc2[mi][3]};
    STORE(i * 64 + tr * 4 + mi, j * 64 + tc * 4, v);
    if (la) *(float4*)&shB[(tr * 4 + mi) * 64 + tc * 4] = v;
  }
  if (la) {
    __syncthreads();
    gj64<64>(shB, rowbuf, Dout, t);
  }
}

// ---------------- postK (MFMA): PK = Minv @ (RHS+LK); writes PKT split-bf16 ----------------
__global__ __launch_bounds__(256) void k_postK(const unsigned short* __restrict__ IVh,
                                               const unsigned short* __restrict__ IVl,
                                               const float* __restrict__ RHST, const float* __restrict__ LKT,
                                               unsigned short* __restrict__ PKh, unsigned short* __restrict__ PKl) {
  int b = blockIdx.x, i0 = blockIdx.y * 64, t = threadIdx.x;
  int lane = t & 63, w = t >> 6, wr = w >> 1, wc = w & 1;
  const unsigned short* Ah = IVh + (size_t)b * 65536;
  const unsigned short* Al = IVl + (size_t)b * 65536;
  int ra0 = i0 + wr * 32 + (lane & 15);
  int ob0 = wc * 32 + (lane & 15);
  int klane = (lane >> 4) * 8;
  f32x4 acc[2][2] = {};
  for (int ks = 0; ks < 256; ks += 32) {
    int kk = ks + klane;
    short8 a0h = ld8(Ah + (size_t)ra0 * 256 + kk);
    short8 a1h = ld8(Ah + (size_t)(ra0 + 16) * 256 + kk);
    short8 a0l = ld8(Al + (size_t)ra0 * 256 + kk);
    short8 a1l = ld8(Al + (size_t)(ra0 + 16) * 256 + kk);
    short8 bh[2], bl[2];
#pragma unroll
    for (int s = 0; s < 2; ++s) {
      int o = ob0 + s * 16;
      float g[8];
      float4 g0 = *(const float4*)&RHST[((size_t)b * 64 + o) * 256 + kk];
      float4 g1 = *(const float4*)&RHST[((size_t)b * 64 + o) * 256 + kk + 4];
      float4 l0 = *(const float4*)&LKT[(size_t)o * 256 + kk];
      float4 l1 = *(const float4*)&LKT[(size_t)o * 256 + kk + 4];
      g[0] = g0.x + l0.x; g[1] = g0.y + l0.y; g[2] = g0.z + l0.z; g[3] = g0.w + l0.w;
      g[4] = g1.x + l1.x; g[5] = g1.y + l1.y; g[6] = g1.z + l1.z; g[7] = g1.w + l1.w;
      cvt8(g, bh[s], bl[s]);
    }
    acc[0][0] = mfma3(a0h, a0l, bh[0], bl[0], acc[0][0]);
    acc[0][1] = mfma3(a0h, a0l, bh[1], bl[1], acc[0][1]);
    acc[1][0] = mfma3(a1h, a1l, bh[0], bl[0], acc[1][0]);
    acc[1][1] = mfma3(a1h, a1l, bh[1], bl[1], acc[1][1]);
  }
#pragma unroll
  for (int ti = 0; ti < 2; ++ti)
#pragma unroll
    for (int tj = 0; tj < 2; ++tj) {
      int ib = i0 + wr * 32 + ti * 16 + (lane >> 4) * 4;
      int o = wc * 32 + tj * 16 + (lane & 15);
      float4 v = {acc[ti][tj][0], acc[ti][tj][1], acc[ti][tj][2], acc[ti][tj][3]};
      uint2 H, L;
      split4(v, H, L);
      *(uint2*)&PKh[((size_t)b * 64 + o) * 256 + ib] = H;
      *(uint2*)&PKl[((size_t)b * 64 + o) * 256 + ib] = L;
    }
}

// ---------------- mu + spread (MFMA, phi_q inline-split) ----------------
__global__ __launch_bounds__(256) void k_musp(const float* __restrict__ phi_q,
                                              const unsigned short* __restrict__ IVh,
                                              const unsigned short* __restrict__ IVl,
                                              const unsigned short* __restrict__ PKh,
                                              const unsigned short* __restrict__ PKl, float* __restrict__ mu,
                                              float* __restrict__ spread) {
  int b = blockIdx.x, qb = blockIdx.y * 64, t = threadIdx.x;
  int lane = t & 63, w = t >> 6;
  int qs = qb + w * 16;
  int qlane = qs + (lane & 15);
  int klane = (lane >> 4) * 8;
  const float* Pq = phi_q + (size_t)b * 512 * 256;
  short8 ah[8], al[8];
#pragma unroll
  for (int k8 = 0; k8 < 8; ++k8) cvt8(&Pq[(size_t)qlane * 256 + k8 * 32 + klane], ah[k8], al[k8]);
  // mu
  const unsigned short* Kh = PKh + (size_t)b * 64 * 256;
  const unsigned short* Kl = PKl + (size_t)b * 64 * 256;
#pragma unroll
  for (int ot = 0; ot < 4; ++ot) {
    f32x4 acc = {};
    int orow = ot * 16 + (lane & 15);
#pragma unroll
    for (int k8 = 0; k8 < 8; ++k8) {
      short8 bh = ld8(Kh + (size_t)orow * 256 + k8 * 32 + klane);
      short8 bl = ld8(Kl + (size_t)orow * 256 + k8 * 32 + klane);
      acc = mfma3(ah[k8], al[k8], bh, bl, acc);
    }
#pragma unroll
    for (int r = 0; r < 4; ++r)
      mu[((size_t)b * 512 + qs + (lane >> 4) * 4 + r) * 64 + ot * 16 + (lane & 15)] = acc[r];
  }
  // spread
  const unsigned short* Vh = IVh + (size_t)b * 65536;
  const unsigned short* Vl = IVl + (size_t)b * 65536;
  float rs[4] = {0.f, 0.f, 0.f, 0.f};
  for (int jt = 0; jt < 16; ++jt) {
    f32x4 acc = {};
    int jrow = jt * 16 + (lane & 15);
#pragma unroll
    for (int k8 = 0; k8 < 8; ++k8) {
      short8 bh = ld8(Vh + (size_t)jrow * 256 + k8 * 32 + klane);
      short8 bl = ld8(Vl + (size_t)jrow * 256 + k8 * 32 + klane);
      acc = mfma3(ah[k8], al[k8], bh, bl, acc);
    }
#pragma unroll
    for (int r = 0; r < 4; ++r) {
      int q = qs + (lane >> 4) * 4 + r;
      rs[r] += acc[r] * Pq[(size_t)q * 256 + jt * 16 + (lane & 15)];
    }
  }
#pragma unroll
  for (int off = 1; off < 16; off <<= 1)
#pragma unroll
    for (int r = 0; r < 4; ++r) rs[r] += __shfl_xor(rs[r], off);
  if ((lane & 15) == 0) {
#pragma unroll
    for (int r = 0; r < 4; ++r) spread[(size_t)b * 512 + qs + (lane >> 4) * 4 + r] = 1.0f + rs[r];
  }
}

// ---------------- sig fill + nll ----------------
__global__ __launch_bounds__(256) void k_signll(const float* __restrict__ spread, float4* __restrict__ sig,
                                                const float* __restrict__ yq, const float* __restrict__ mu,
                                                float* __restrict__ nllacc) {
  int t = threadIdx.x;
  if (blockIdx.x < 65536) {
    size_t idx = (size_t)blockIdx.x * 256 + t;
    int p4 = (int)(idx & 15);
    int o = (int)((idx >> 4) & 63);
    size_t bq = idx >> 10;
    float sv = spread[bq] * SIG_EPS;
    float4 v;
    v.x = (p4 * 4 + 0 == o) ? sv : 0.f;
    v.y = (p4 * 4 + 1 == o) ? sv : 0.f;
    v.z = (p4 * 4 + 2 == o) ? sv : 0.f;
    v.w = (p4 * 4 + 3 == o) ? sv : 0.f;
    sig[idx] = v;
  } else {
    int bq = (blockIdx.x - 65536) * 256 + t;
    float sp = spread[bq];
    const float4* yv = (const float4*)(yq + (size_t)bq * 64);
    const float4* mv = (const float4*)(mu + (size_t)bq * 64);
    float ssd = 0.f;
#pragma unroll
    for (int i = 0; i < 16; ++i) {
      float4 a = yv[i], b = mv[i];
      float dx = a.x - b.x, dy = a.y - b.y, dz = a.z - b.z, dw = a.w - b.w;
      ssd += dx * dx + dy * dy + dz * dz + dw * dw;
    }
    float quadf = ssd / (sp * SIG_EPS);
    float ld = 64.0f * (logf(sp) + LOG_SIG_EPS);
    float val = (ld + quadf) * (1.0f / 16384.0f);
#pragma unroll
    for (int off = 32; off; off >>= 1) val += __shfl_down(val, off);
    if ((t & 63) == 0) atomicAdd(nllacc, val);
  }
}

__global__ void k_fin(const float* __restrict__ nllacc, float* __restrict__ out) {
  if (threadIdx.x == 0 && blockIdx.x == 0) out[0] = nllacc[0];
}

extern "C" void kernel_launch(void* const* d_in, const int* in_sizes, int n_in, void* d_out, int out_size,
                              void* d_ws, size_t ws_size, hipStream_t stream) {
  const float* phi_s = (const float*)d_in[0];
  const float* y_s = (const float*)d_in[1];
  const float* phi_q = (const float*)d_in[2];
  const float* y_q = (const float*)d_in[3];
  const float* Km = (const float*)d_in[4];
  const float* La = (const float*)d_in[5];

  float* ws = (float*)d_ws;
  float* Lm = ws + WS_L;
  float* T1 = ws + WS_T1;
  float* LKT = ws + WS_LKT;
  float* M0 = ws + WS_M0;
  float* M1 = ws + WS_M1;
  float* RHST = ws + WS_RHST;
  float* Dbuf = ws + WS_D;
  float* spread = ws + WS_SP;
  float* nllacc = ws + WS_NLL;
  unsigned short* u16b = (unsigned short*)(ws + WS_U16);
  unsigned short* PTh = u16b + U_PTH;
  unsigned short* PTl = u16b + U_PTL;
  unsigned short* YTh = u16b + U_YTH;
  unsigned short* YTl = u16b + U_YTL;
  unsigned short* IVh = u16b + U_IVH;
  unsigned short* IVl = u16b + U_IVL;
  unsigned short* PKh = u16b + U_PKH;
  unsigned short* PKl = u16b + U_PKL;

  float* out_mu = (float*)d_out;
  float* out_sig = out_mu + OUT_MU_ELEMS;
  float* out_nll = out_mu + OUT_NLL_IDX;

  k_cvt<<<1280, 256, 0, stream>>>(phi_s, y_s, PTh, PTl, YTh, YTl, nllacc);
  k_pre1<<<20, 256, 0, stream>>>(La, Km, Lm, T1);
  k_gram<<<dim3(B, 15), 256, 0, stream>>>(PTh, PTl, YTh, YTl, Lm, La, T1, M0, RHST, LKT, Dbuf);
  k_step<<<dim3(B, 16), 256, 0, stream>>>(M0, M1, Dbuf, IVh, IVl, 0);
  k_step<<<dim3(B, 16), 256, 0, stream>>>(M1, M0, Dbuf, IVh, IVl, 1);
  k_step<<<dim3(B, 16), 256, 0, stream>>>(M0, M1, Dbuf, IVh, IVl, 2);
  k_step<<<dim3(B, 16), 256, 0, stream>>>(M1, M0, Dbuf, IVh, IVl, 3);
  k_postK<<<dim3(B, 4), 256, 0, stream>>>(IVh, IVl, RHST, LKT, PKh, PKl);
  k_musp<<<dim3(B, 8), 256, 0, stream>>>(phi_q, IVh, IVl, PKh, PKl, out_mu, spread);
  k_signll<<<65600, 256, 0, stream>>>(spread, (float4*)out_sig, y_q, out_mu, nllacc);
  k_fin<<<1, 64, 0, stream>>>(nllacc, out_nll);
}